// Round 15
// baseline (2608.656 us; speedup 1.0000x reference)
//
#include <hip/hip_runtime.h>
#include <stdint.h>

#define N_NODESC 65536
#define N_EDGESC 1048576
#define HIDC 128
#define NUM_GRAPHSC 512
#define NUM_CLASSESC 10
#define NUM_EXPERTSC 4
#define NUM_LAYERSC 3

static const size_t NH = (size_t)N_NODESC * HIDC;

typedef __attribute__((ext_vector_type(8))) short short8v;   // 8 bf16 = 4 VGPR
typedef __attribute__((ext_vector_type(4))) float float4v;   // MFMA C/D

// ---------------- threefry2x32 (JAX-compatible, 20 rounds) ----------------
__host__ __device__ __forceinline__ uint32_t rotl32(uint32_t v, int r) {
  return (v << r) | (v >> (32 - r));
}
__host__ __device__ inline void threefry2x32(uint32_t k0, uint32_t k1,
                                             uint32_t x0, uint32_t x1,
                                             uint32_t* o0, uint32_t* o1) {
  uint32_t k2 = k0 ^ k1 ^ 0x1BD11BDAu;
  x0 += k0; x1 += k1;
#define TF_R(r) x0 += x1; x1 = rotl32(x1, r); x1 ^= x0;
  TF_R(13) TF_R(15) TF_R(26) TF_R(6)
  x0 += k1; x1 += k2 + 1u;
  TF_R(17) TF_R(29) TF_R(16) TF_R(24)
  x0 += k2; x1 += k0 + 2u;
  TF_R(13) TF_R(15) TF_R(26) TF_R(6)
  x0 += k0; x1 += k1 + 3u;
  TF_R(17) TF_R(29) TF_R(16) TF_R(24)
  x0 += k1; x1 += k2 + 4u;
  TF_R(13) TF_R(15) TF_R(26) TF_R(6)
  x0 += k2; x1 += k0 + 5u;
#undef TF_R
  *o0 = x0; *o1 = x1;
}

__device__ __forceinline__ float uniform_from_bits(uint32_t b) {
  float f = __uint_as_float((b >> 9) | 0x3f800000u) - 1.0f;
  const float mn = 1e-6f;
  const float mx = 1.0f - 1e-6f;
  return fmaxf(mn, __fadd_rn(__fmul_rn(f, __fsub_rn(mx, mn)), mn));
}

// f32-faithful hard-concrete decision (fast path + CR borderline replay)
__device__ __forceinline__ float hc_decide(float l, uint32_t key0, uint32_t key1,
                                           uint32_t i) {
  uint32_t o0, o1;
  threefry2x32(key0, key1, 0u, i, &o0, &o1);
  float u = uniform_from_bits(o0 ^ o1);
  float tf = -__logf(u);
  float gf = -__logf(tf);
  float margf = l + gf;
  if (fabsf(margf) > 1e-4f) return (margf > 0.0f) ? 1.0f : 0.0f;
  float t32 = (float)(-log((double)u));
  float g32 = (float)(-log((double)t32));
  float m32 = __fadd_rn(l, g32);
  float q = m32 / 0.1f;
  float e32 = (float)exp(-(double)q);
  float den = __fadd_rn(1.0f, e32);
  float s = 1.0f / den;
  return (s > 0.5f) ? 1.0f : 0.0f;
}

// ---------------- bf16 helpers ----------------
__device__ __forceinline__ float bf2f(unsigned short u) {
  return __uint_as_float(((uint32_t)u) << 16);
}
__device__ __forceinline__ unsigned short f2bf(float v) {
  uint32_t u = __float_as_uint(v);
  return (unsigned short)((u + 0x7FFFu + ((u >> 16) & 1u)) >> 16);
}

// ---------------- CSR build (full graph, eid-sorted for f32 exactness) -----
__global__ void khist(const int* __restrict__ dst, int* __restrict__ deg) {
  int e = blockIdx.x * 256 + threadIdx.x;
  if (e < N_EDGESC) atomicAdd(&deg[dst[e]], 1);
}

__global__ void kscan(const int* __restrict__ deg, int* __restrict__ offs) {
  __shared__ int part[1024];
  int t = threadIdx.x;
  int base = t * 64;
  int s = 0;
  for (int i = 0; i < 64; ++i) s += deg[base + i];
  part[t] = s;
  __syncthreads();
  for (int off = 1; off < 1024; off <<= 1) {
    int v = 0;
    if (t >= off) v = part[t - off];
    __syncthreads();
    part[t] += v;
    __syncthreads();
  }
  int run = part[t] - s;
  for (int i = 0; i < 64; ++i) {
    int d = deg[base + i];
    offs[base + i] = run;
    run += d;
  }
  if (t == 1023) offs[N_NODESC] = run;
}

__global__ void kfill(const int* __restrict__ src, const int* __restrict__ dst,
                      int* __restrict__ curs, int* __restrict__ csr_src,
                      int* __restrict__ csr_eid) {
  int e = blockIdx.x * 256 + threadIdx.x;
  if (e >= N_EDGESC) return;
  int d = dst[e];
  int p = atomicAdd(&curs[d], 1);
  csr_src[p] = src[e];
  csr_eid[p] = e;
}

__global__ void ksort(const int* __restrict__ offs, int* __restrict__ csr_src,
                      int* __restrict__ csr_eid) {
  int n = blockIdx.x * 256 + threadIdx.x;
  if (n >= N_NODESC) return;
  int s = offs[n], e = offs[n + 1];
  for (int i = s + 1; i < e; ++i) {
    int ke = csr_eid[i], ks = csr_src[i];
    int j = i - 1;
    while (j >= s && csr_eid[j] > ke) {
      csr_eid[j + 1] = csr_eid[j];
      csr_src[j + 1] = csr_src[j];
      --j;
    }
    csr_eid[j + 1] = ke;
    csr_src[j + 1] = ks;
  }
}

__global__ void kbounds(const int* __restrict__ batch, int* __restrict__ bounds) {
  int g = threadIdx.x;
  int lo = 0, hi = N_NODESC;
  while (lo < hi) {
    int mid = (lo + hi) >> 1;
    if (batch[mid] < g) lo = mid + 1; else hi = mid;
  }
  bounds[g] = lo;
  if (g == 0) bounds[NUM_GRAPHSC] = N_NODESC;
}

// ---------------- f32 GIN gather (clean encoder; bit-exact, 4-wide ILP) ----
__global__ void gather_z(const float* __restrict__ hin,
                         const int* __restrict__ offs,
                         const int* __restrict__ csr_src,
                         const float* __restrict__ epsArr, int l,
                         float* __restrict__ zout) {
  int gt = blockIdx.x * blockDim.x + threadIdx.x;
  int n = gt >> 6;
  int lane = gt & 63;
  if (n >= N_NODESC) return;
  int s = offs[n], e = offs[n + 1];
  float ax = 0.f, ay = 0.f;
  int i = s;
  for (; i + 4 <= e; i += 4) {
    int s0 = csr_src[i], s1 = csr_src[i + 1], s2 = csr_src[i + 2], s3 = csr_src[i + 3];
    const float2 v0 = *(const float2*)&hin[(size_t)s0 * HIDC + lane * 2];
    const float2 v1 = *(const float2*)&hin[(size_t)s1 * HIDC + lane * 2];
    const float2 v2 = *(const float2*)&hin[(size_t)s2 * HIDC + lane * 2];
    const float2 v3 = *(const float2*)&hin[(size_t)s3 * HIDC + lane * 2];
    ax = __fadd_rn(ax, v0.x); ay = __fadd_rn(ay, v0.y);
    ax = __fadd_rn(ax, v1.x); ay = __fadd_rn(ay, v1.y);
    ax = __fadd_rn(ax, v2.x); ay = __fadd_rn(ay, v2.y);
    ax = __fadd_rn(ax, v3.x); ay = __fadd_rn(ay, v3.y);
  }
  for (; i < e; ++i) {
    int sn = csr_src[i];
    const float2 v = *(const float2*)&hin[(size_t)sn * HIDC + lane * 2];
    ax = __fadd_rn(ax, v.x);
    ay = __fadd_rn(ay, v.y);
  }
  float ep = __fadd_rn(1.0f, epsArr[l]);
  const float2 hv = *(const float2*)&hin[(size_t)n * HIDC + lane * 2];
  ax = __fadd_rn(__fmul_rn(ep, hv.x), ax);
  ay = __fadd_rn(__fmul_rn(ep, hv.y), ay);
  float2 o; o.x = ax; o.y = ay;
  *(float2*)&zout[(size_t)n * HIDC + lane * 2] = o;
}

// ---------------- f32 K-split GEMM (bit-exact chain; 2 phases of K=64) -----
// Round-13 proven layout: LDS 64KB, 2 blocks/CU. FMA chain k ascending,
// single accumulator. Swizzle byte = k*512 + MXOR(m) ^ KX(k) (2-way writes).
// NOTE: MXOR(m+4) != MXOR(m)+16 when (m&32) — compute MXOR at the exact row.
__device__ __forceinline__ int MXOR(int m) { return (m * 4) ^ ((m & 96) >> 1); }
__device__ __forceinline__ int KX(int k) { return ((k >> 2) & 7) << 4; }

template <typename EPI>
__device__ __forceinline__ void gemm_core(const float* __restrict__ Xf,
                                          const float* __restrict__ W,
                                          const float* __restrict__ bias,
                                          int doRelu, int tile, EPI epi) {
  __shared__ char sXb[64 * 512];
  __shared__ char sWb[64 * 512];
  const int tid = threadIdx.x;
  const size_t base = (size_t)tile * HIDC * HIDC;
  const int tm = (tid >> 4) << 3;
  const int tn = (tid & 15) << 3;
  const int xA = MXOR(tm), xA2 = MXOR(tm + 4);
  const int xB = MXOR(tn), xB2 = MXOR(tn + 4);

  float acc[8][8];
#pragma unroll
  for (int i = 0; i < 8; ++i)
#pragma unroll
    for (int j = 0; j < 8; ++j) acc[i][j] = 0.0f;

  for (int kh = 0; kh < 2; ++kh) {
    __syncthreads();
#pragma unroll
    for (int i = 0; i < 8; ++i) {
      int idx = tid + 256 * i;
      int m = idx >> 4;
      int kq = (idx & 15) * 4;
      float4 v = *(const float4*)(Xf + base + (size_t)m * HIDC + kh * 64 + kq);
      int mo = MXOR(m);
      *(float*)(sXb + (kq + 0) * 512 + (mo ^ KX(kq + 0))) = v.x;
      *(float*)(sXb + (kq + 1) * 512 + (mo ^ KX(kq + 1))) = v.y;
      *(float*)(sXb + (kq + 2) * 512 + (mo ^ KX(kq + 2))) = v.z;
      *(float*)(sXb + (kq + 3) * 512 + (mo ^ KX(kq + 3))) = v.w;
    }
#pragma unroll
    for (int i = 0; i < 8; ++i) {
      int idx = tid + 256 * i;
      int kk = idx >> 5;
      int n0 = (idx & 31) * 4;
      float4 v = *(const float4*)(W + (size_t)(kh * 64 + kk) * HIDC + n0);
      *(float4*)(sWb + kk * 512 + (MXOR(n0) ^ KX(kk))) = v;
    }
    __syncthreads();

#pragma unroll 4
    for (int kk = 0; kk < 64; ++kk) {
      int kx = KX(kk);
      float4 a0 = *(const float4*)(sXb + kk * 512 + (xA ^ kx));
      float4 a1 = *(const float4*)(sXb + kk * 512 + (xA2 ^ kx));
      float4 b0 = *(const float4*)(sWb + kk * 512 + (xB ^ kx));
      float4 b1 = *(const float4*)(sWb + kk * 512 + (xB2 ^ kx));
      float a[8] = {a0.x, a0.y, a0.z, a0.w, a1.x, a1.y, a1.z, a1.w};
      float b[8] = {b0.x, b0.y, b0.z, b0.w, b1.x, b1.y, b1.z, b1.w};
#pragma unroll
      for (int i = 0; i < 8; ++i)
#pragma unroll
        for (int j = 0; j < 8; ++j) acc[i][j] = fmaf(a[i], b[j], acc[i][j]);
    }
  }

  float bvals[8];
#pragma unroll
  for (int j = 0; j < 8; ++j) bvals[j] = bias ? bias[tn + j] : 0.0f;
#pragma unroll
  for (int i = 0; i < 8; ++i) {
    float r[8];
#pragma unroll
    for (int j = 0; j < 8; ++j) {
      float v = __fadd_rn(acc[i][j], bvals[j]);
      if (doRelu) v = fmaxf(v, 0.0f);
      r[j] = v;
    }
    epi(tile * HIDC + tm + i, tn, r);
  }
}

__global__ __launch_bounds__(256, 2)
void gemm_f32(const float* __restrict__ X, const float* __restrict__ W,
              const float* __restrict__ bias, float* __restrict__ O, int doRelu) {
  gemm_core(X, W, bias, doRelu, blockIdx.x,
            [&](int row, int tn, const float* r) {
              float* orow = O + (size_t)row * HIDC + tn;
              *(float4*)&orow[0] = *(const float4*)&r[0];
              *(float4*)&orow[4] = *(const float4*)&r[4];
            });
}

// 4 mask GEMMs of one expert; slice 0 fuses rowdot (16-lane butterfly) +
// node hard-concrete decision -> outNode, never touching global t1.
__global__ __launch_bounds__(256, 2)
void gemm_f32x4(const float* __restrict__ X,
                const float* W0, const float* W1, const float* W2, const float* W3,
                const float* b0, const float* b1,
                const float* __restrict__ nw2, const float* __restrict__ nb2,
                uint32_t key0, uint32_t key1, float* __restrict__ outNode,
                float* o1, float* o2, float* o3) {
  int slice = blockIdx.x >> 9;
  int tile = blockIdx.x & 511;
  if (slice == 0) {
    const int tn0 = (threadIdx.x & 15) << 3;
    float w2v[8];
#pragma unroll
    for (int j = 0; j < 8; ++j) w2v[j] = nw2[tn0 + j];
    float b2s = nb2[0];
    gemm_core(X, W0, b0, 1, tile,
              [&](int row, int tn, const float* r) {
                float pd = 0.0f;
#pragma unroll
                for (int j = 0; j < 8; ++j) pd = fmaf(r[j], w2v[j], pd);
                pd += __shfl_xor(pd, 1, 16);
                pd += __shfl_xor(pd, 2, 16);
                pd += __shfl_xor(pd, 4, 16);
                pd += __shfl_xor(pd, 8, 16);
                if ((threadIdx.x & 15) == (row & 7)) {
                  float l = pd + b2s;
                  outNode[(size_t)row * NUM_EXPERTSC] =
                      hc_decide(l, key0, key1, (uint32_t)row);
                }
              });
  } else {
    const float* W; const float* bias; float* O; int relu;
    if (slice == 1)      { W = W1; bias = b1; O = o1; relu = 1; }
    else if (slice == 2) { W = W2; bias = nullptr; O = o2; relu = 0; }
    else                 { W = W3; bias = nullptr; O = o3; relu = 0; }
    gemm_core(X, W, bias, relu, tile,
              [&](int row, int tn, const float* r) {
                float* orow = O + (size_t)row * HIDC + tn;
                *(float4*)&orow[0] = *(const float4*)&r[0];
                *(float4*)&orow[4] = *(const float4*)&r[4];
              });
  }
}

// feat GEMM layer 2 + fused hard-concrete decisions -> out[OFF_FEAT..]
__global__ __launch_bounds__(256, 2)
void gemm_feat(const float* __restrict__ X, const float* __restrict__ W,
               const float* __restrict__ bias, uint32_t key0, uint32_t key1,
               float* __restrict__ outFeat /* + k*HIDC already */) {
  gemm_core(X, W, bias, 0, blockIdx.x,
            [&](int row, int tn, const float* r) {
              float d[8];
#pragma unroll
              for (int j = 0; j < 8; ++j)
                d[j] = hc_decide(r[j], key0, key1,
                                 (uint32_t)(row * HIDC + tn + j));
              float* orow = outFeat + (size_t)row * (NUM_EXPERTSC * HIDC) + tn;
              *(float4*)&orow[0] = *(const float4*)&d[0];
              *(float4*)&orow[4] = *(const float4*)&d[4];
            });
}

// ---------------- weight prep: f32 [k][n] -> bf16 transposed [n][k] --------
__global__ void kprepW(const float* __restrict__ kw1, const float* __restrict__ kw2,
                       unsigned short* __restrict__ Wt) {
  int t = blockIdx.x * 256 + threadIdx.x;   // 6 mats * 2048 uint4-chunks
  int mat = t >> 11;
  int r = t & 2047;
  int n = r >> 4;
  int kkc = r & 15;
  const float* W = (mat < 3) ? (kw1 + (size_t)mat * HIDC * HIDC)
                             : (kw2 + (size_t)(mat - 3) * HIDC * HIDC);
  unsigned short pk[8];
#pragma unroll
  for (int j = 0; j < 8; ++j)
    pk[j] = f2bf(W[(size_t)(kkc * 8 + j) * HIDC + n]);
  *(uint4*)(Wt + (size_t)mat * HIDC * HIDC + (size_t)n * HIDC + kkc * 8) =
      *(uint4*)pk;
}

// ------ bf16 MFMA fused layer: h2 = act2(relu(X@W1+b1)@W2+b2) --------------
// One 128x128 tile per block; h1 round-trips through LDS (bf16, same f2bf
// rounding as a global round-trip -> numerics identical).
// LDS swizzle: 16B-chunk index ^= (row&7).  Frag layouts per m89/m91.
__global__ __launch_bounds__(256, 2)
void gemm_mfma2(const unsigned short* __restrict__ Xpool,
                const unsigned short* __restrict__ Wt1,
                const unsigned short* __restrict__ Wt2,
                const float* __restrict__ bias1, const float* __restrict__ bias2,
                unsigned short* __restrict__ Opool, int doRelu2) {
  __shared__ unsigned short sX[128 * 128];
  __shared__ unsigned short sW[128 * 128];
  const int tid = threadIdx.x;
  const int kex = blockIdx.x >> 9;
  const int tile = blockIdx.x & 511;
  const unsigned short* X = Xpool + (size_t)kex * NH + (size_t)tile * HIDC * HIDC;
  unsigned short* O = Opool + (size_t)kex * NH + (size_t)tile * HIDC * HIDC;

  const int lane = tid & 63;
  const int wid = tid >> 6;
  const int wm = wid * 32;
  const int lrow = lane & 15;
  const int lk = (lane >> 4) * 4;
  union FU { uint2 u2[2]; short8v s8; };

#pragma unroll
  for (int i = 0; i < 8; ++i) {
    int idx = tid + 256 * i;
    int r = idx >> 4;
    int cc = idx & 15;
    uint4 vx = *(const uint4*)(X + (size_t)r * HIDC + cc * 8);
    uint4 vw = *(const uint4*)(Wt1 + (size_t)r * HIDC + cc * 8);
    int sc = (cc ^ (r & 7)) * 8;
    *(uint4*)(sX + r * HIDC + sc) = vx;
    *(uint4*)(sW + r * HIDC + sc) = vw;
  }
  __syncthreads();

  float4v acc[2][8];
#pragma unroll
  for (int rt = 0; rt < 2; ++rt)
#pragma unroll
    for (int nt = 0; nt < 8; ++nt) acc[rt][nt] = (float4v)0.0f;

  for (int kc = 0; kc < 128; kc += 32) {
    int kb = kc + lk;
    short8v afr[2], bfr[8];
#pragma unroll
    for (int rt = 0; rt < 2; ++rt) {
      int row = wm + rt * 16 + lrow;
      const unsigned short* basep = sX + row * HIDC;
      int s0 = (((kb) >> 3) ^ (row & 7)) * 8 + (kb & 7);
      int s1 = (((kb + 16) >> 3) ^ (row & 7)) * 8 + (kb & 7);
      FU u;
      u.u2[0] = *(const uint2*)(basep + s0);
      u.u2[1] = *(const uint2*)(basep + s1);
      afr[rt] = u.s8;
    }
#pragma unroll
    for (int nt = 0; nt < 8; ++nt) {
      int row = nt * 16 + lrow;
      const unsigned short* basep = sW + row * HIDC;
      int s0 = (((kb) >> 3) ^ (row & 7)) * 8 + (kb & 7);
      int s1 = (((kb + 16) >> 3) ^ (row & 7)) * 8 + (kb & 7);
      FU u;
      u.u2[0] = *(const uint2*)(basep + s0);
      u.u2[1] = *(const uint2*)(basep + s1);
      bfr[nt] = u.s8;
    }
#pragma unroll
    for (int rt = 0; rt < 2; ++rt)
#pragma unroll
      for (int nt = 0; nt < 8; ++nt)
        acc[rt][nt] = __builtin_amdgcn_mfma_f32_16x16x32_bf16(
            afr[rt], bfr[nt], acc[rt][nt], 0, 0, 0);
  }
  __syncthreads();

  // h1 -> sX (bf16, swizzled); stage W2 -> sW
#pragma unroll
  for (int nt = 0; nt < 8; ++nt) {
    float bv = bias1[nt * 16 + lrow];
#pragma unroll
    for (int rt = 0; rt < 2; ++rt) {
#pragma unroll
      for (int j = 0; j < 4; ++j) {
        float v = fmaxf(acc[rt][nt][j] + bv, 0.0f);
        int row = wm + rt * 16 + (lane >> 4) * 4 + j;
        int col = nt * 16 + lrow;
        int sc = (((col >> 3) ^ (row & 7)) * 8) + (col & 7);
        sX[row * HIDC + sc] = f2bf(v);
      }
    }
  }
#pragma unroll
  for (int i = 0; i < 8; ++i) {
    int idx = tid + 256 * i;
    int r = idx >> 4;
    int cc = idx & 15;
    uint4 vw = *(const uint4*)(Wt2 + (size_t)r * HIDC + cc * 8);
    *(uint4*)(sW + r * HIDC + ((cc ^ (r & 7)) * 8)) = vw;
  }
  __syncthreads();

#pragma unroll
  for (int rt = 0; rt < 2; ++rt)
#pragma unroll
    for (int nt = 0; nt < 8; ++nt) acc[rt][nt] = (float4v)0.0f;

  for (int kc = 0; kc < 128; kc += 32) {
    int kb = kc + lk;
    short8v afr[2], bfr[8];
#pragma unroll
    for (int rt = 0; rt < 2; ++rt) {
      int row = wm + rt * 16 + lrow;
      const unsigned short* basep = sX + row * HIDC;
      int s0 = (((kb) >> 3) ^ (row & 7)) * 8 + (kb & 7);
      int s1 = (((kb + 16) >> 3) ^ (row & 7)) * 8 + (kb & 7);
      FU u;
      u.u2[0] = *(const uint2*)(basep + s0);
      u.u2[1] = *(const uint2*)(basep + s1);
      afr[rt] = u.s8;
    }
#pragma unroll
    for (int nt = 0; nt < 8; ++nt) {
      int row = nt * 16 + lrow;
      const unsigned short* basep = sW + row * HIDC;
      int s0 = (((kb) >> 3) ^ (row & 7)) * 8 + (kb & 7);
      int s1 = (((kb + 16) >> 3) ^ (row & 7)) * 8 + (kb & 7);
      FU u;
      u.u2[0] = *(const uint2*)(basep + s0);
      u.u2[1] = *(const uint2*)(basep + s1);
      bfr[nt] = u.s8;
    }
#pragma unroll
    for (int rt = 0; rt < 2; ++rt)
#pragma unroll
      for (int nt = 0; nt < 8; ++nt)
        acc[rt][nt] = __builtin_amdgcn_mfma_f32_16x16x32_bf16(
            afr[rt], bfr[nt], acc[rt][nt], 0, 0, 0);
  }

#pragma unroll
  for (int nt = 0; nt < 8; ++nt) {
    float bv = bias2[nt * 16 + lrow];
#pragma unroll
    for (int rt = 0; rt < 2; ++rt) {
#pragma unroll
      for (int j = 0; j < 4; ++j) {
        float v = acc[rt][nt][j] + bv;
        if (doRelu2) v = fmaxf(v, 0.0f);
        int row = wm + rt * 16 + (lane >> 4) * 4 + j;
        O[(size_t)row * HIDC + nt * 16 + lrow] = f2bf(v);
      }
    }
  }
}

// -------- edge logits: 16-lane group per edge, 4 edges/wave concurrent ------
__global__ void edge_csrK(const float* __restrict__ A, const float* __restrict__ Bm,
                          const float* __restrict__ b1, const float* __restrict__ w2,
                          const float* __restrict__ b2,
                          const int* __restrict__ offs, const int* __restrict__ csr_src,
                          const int* __restrict__ csr_eid,
                          uint32_t key0, uint32_t key1,
                          float* __restrict__ outp, unsigned char* __restrict__ mcsr) {
  int n = blockIdx.x * 4 + (threadIdx.x >> 6);
  int lane = threadIdx.x & 63;
  int g = lane >> 4;
  int gl = lane & 15;
  const float4* Bv = (const float4*)&Bm[(size_t)n * HIDC + gl * 8];
  float4 b_lo = Bv[0], b_hi = Bv[1];
  float4 bb_lo = *(const float4*)&b1[gl * 8];
  float4 bb_hi = *(const float4*)&b1[gl * 8 + 4];
  float4 w_lo = *(const float4*)&w2[gl * 8];
  float4 w_hi = *(const float4*)&w2[gl * 8 + 4];
  float bscalar = b2[0];
  int s = offs[n], e = offs[n + 1];
  for (int i = s; i < e; i += 4) {
    int cnt = e - i; if (cnt > 4) cnt = 4;
    float p = 0.0f;
    if (g < cnt) {
      int sg = csr_src[i + g];
      const float4* Av = (const float4*)&A[(size_t)sg * HIDC + gl * 8];
      float4 a_lo = Av[0], a_hi = Av[1];
      float h;
      h = fmaxf(__fadd_rn(__fadd_rn(a_lo.x, b_lo.x), bb_lo.x), 0.0f); p = fmaf(h, w_lo.x, p);
      h = fmaxf(__fadd_rn(__fadd_rn(a_lo.y, b_lo.y), bb_lo.y), 0.0f); p = fmaf(h, w_lo.y, p);
      h = fmaxf(__fadd_rn(__fadd_rn(a_lo.z, b_lo.z), bb_lo.z), 0.0f); p = fmaf(h, w_lo.z, p);
      h = fmaxf(__fadd_rn(__fadd_rn(a_lo.w, b_lo.w), bb_lo.w), 0.0f); p = fmaf(h, w_lo.w, p);
      h = fmaxf(__fadd_rn(__fadd_rn(a_hi.x, b_hi.x), bb_hi.x), 0.0f); p = fmaf(h, w_hi.x, p);
      h = fmaxf(__fadd_rn(__fadd_rn(a_hi.y, b_hi.y), bb_hi.y), 0.0f); p = fmaf(h, w_hi.y, p);
      h = fmaxf(__fadd_rn(__fadd_rn(a_hi.z, b_hi.z), bb_hi.z), 0.0f); p = fmaf(h, w_hi.z, p);
      h = fmaxf(__fadd_rn(__fadd_rn(a_hi.w, b_hi.w), bb_hi.w), 0.0f); p = fmaf(h, w_hi.w, p);
    }
    p += __shfl_xor(p, 1, 16);
    p += __shfl_xor(p, 2, 16);
    p += __shfl_xor(p, 4, 16);
    p += __shfl_xor(p, 8, 16);
    if (g < cnt && gl == 0) {
      int eid = csr_eid[i + g];
      float l = p + bscalar;
      float mval = hc_decide(l, key0, key1, (uint32_t)eid);
      outp[(size_t)eid * NUM_EXPERTSC] = mval;
      mcsr[i + g] = (unsigned char)mval;
    }
  }
}

// ---------------- masked_x (bf16), batched 4 experts ----------------
__global__ void kmaskxB(const float* __restrict__ x, const float* __restrict__ nmaskb,
                        const float* __restrict__ fmaskb,
                        unsigned short* __restrict__ hbpool) {
  int k = blockIdx.x >> 13;
  int t = (blockIdx.x & 8191) * 256 + threadIdx.x;
  int n = t >> 5;
  int q = (t & 31) << 2;
  float nm = nmaskb[(size_t)n * NUM_EXPERTSC + k];
  float4 xv = *(const float4*)&x[(size_t)n * HIDC + q];
  float4 fv = *(const float4*)&fmaskb[(size_t)n * (NUM_EXPERTSC * HIDC) + k * HIDC + q];
  ushort2 p0, p1;
  p0.x = f2bf(xv.x * nm * fv.x); p0.y = f2bf(xv.y * nm * fv.y);
  p1.x = f2bf(xv.z * nm * fv.z); p1.y = f2bf(xv.w * nm * fv.w);
  uint2 pk; pk.x = (uint32_t)p0.x | ((uint32_t)p0.y << 16);
  pk.y = (uint32_t)p1.x | ((uint32_t)p1.y << 16);
  *(uint2*)(hbpool + (size_t)k * NH + (size_t)n * HIDC + q) = pk;
}

// -------- bf16 GIN gather, full CSR + positional mask bytes ----------------
__global__ void gatherC(const unsigned short* __restrict__ hpool,
                        const int* __restrict__ offs,
                        const int* __restrict__ csr_src,
                        const unsigned char* __restrict__ mcsr,
                        const float* __restrict__ epsArr, int l,
                        unsigned short* __restrict__ aggpool) {
  int gid = blockIdx.x * 4 + (threadIdx.x >> 6);
  int lane = threadIdx.x & 63;
  int k = gid >> 16;
  int n = gid & 65535;
  const unsigned short* h = hpool + (size_t)k * NH;
  const unsigned char* mc = mcsr + (size_t)k * N_EDGESC;
  int s = offs[n], e = offs[n + 1];
  float ax = 0.f, ay = 0.f;
  for (int base = s; base < e; base += 64) {
    int j = base + lane;
    int valid = (j < e);
    int keep = valid ? (mc[j] != 0) : 0;
    int srcj = valid ? csr_src[j] : 0;
    unsigned long long ball = __ballot(keep);
    while (ball) {
      int l0 = -1, l1 = -1, l2 = -1, l3 = -1;
      l0 = __ffsll((unsigned long long)ball) - 1; ball &= ball - 1;
      if (ball) { l1 = __ffsll((unsigned long long)ball) - 1; ball &= ball - 1; }
      if (ball) { l2 = __ffsll((unsigned long long)ball) - 1; ball &= ball - 1; }
      if (ball) { l3 = __ffsll((unsigned long long)ball) - 1; ball &= ball - 1; }
      int s0 = __shfl(srcj, l0, 64);
      int s1 = (l1 >= 0) ? __shfl(srcj, l1, 64) : 0;
      int s2 = (l2 >= 0) ? __shfl(srcj, l2, 64) : 0;
      int s3 = (l3 >= 0) ? __shfl(srcj, l3, 64) : 0;
      uint32_t v0 = *(const uint32_t*)(h + (size_t)s0 * HIDC + lane * 2);
      uint32_t v1 = (l1 >= 0) ? *(const uint32_t*)(h + (size_t)s1 * HIDC + lane * 2) : 0;
      uint32_t v2 = (l2 >= 0) ? *(const uint32_t*)(h + (size_t)s2 * HIDC + lane * 2) : 0;
      uint32_t v3 = (l3 >= 0) ? *(const uint32_t*)(h + (size_t)s3 * HIDC + lane * 2) : 0;
      ax += __uint_as_float(v0 << 16); ay += __uint_as_float(v0 & 0xFFFF0000u);
      if (l1 >= 0) { ax += __uint_as_float(v1 << 16); ay += __uint_as_float(v1 & 0xFFFF0000u); }
      if (l2 >= 0) { ax += __uint_as_float(v2 << 16); ay += __uint_as_float(v2 & 0xFFFF0000u); }
      if (l3 >= 0) { ax += __uint_as_float(v3 << 16); ay += __uint_as_float(v3 & 0xFFFF0000u); }
    }
  }
  float ep = 1.0f + epsArr[l];
  uint32_t hv = *(const uint32_t*)(h + (size_t)n * HIDC + lane * 2);
  ax = fmaf(ep, __uint_as_float(hv << 16), ax);
  ay = fmaf(ep, __uint_as_float(hv & 0xFFFF0000u), ay);
  uint32_t pk = (uint32_t)f2bf(ax) | ((uint32_t)f2bf(ay) << 16);
  *(uint32_t*)(aggpool + (size_t)k * NH + (size_t)n * HIDC + lane * 2) = pk;
}

// ---------------- mean pool (f32, clean Z) ----------------
__global__ void pool(const float* __restrict__ h, const int* __restrict__ bounds,
                     float* __restrict__ outp, int rowStride) {
  int g = blockIdx.x, j = threadIdx.x;
  int s = bounds[g], e = bounds[g + 1];
  float acc = 0.0f;
  for (int i = s; i < e; ++i) acc = __fadd_rn(acc, h[(size_t)i * HIDC + j]);
  int cnt = e - s; if (cnt < 1) cnt = 1;
  outp[(size_t)g * rowStride + j] = acc / (float)cnt;
}

// ---------------- mean pool (bf16 input), batched 4 experts ----------------
__global__ void poolB(const unsigned short* __restrict__ hbpool,
                      const int* __restrict__ bounds, float* __restrict__ outp) {
  int k = blockIdx.x >> 9;
  int g = blockIdx.x & 511;
  int j = threadIdx.x;
  const unsigned short* h = hbpool + (size_t)k * NH;
  int s = bounds[g], e = bounds[g + 1];
  float acc = 0.0f;
  for (int i = s; i < e; ++i) acc += bf2f(h[(size_t)i * HIDC + j]);
  int cnt = e - s; if (cnt < 1) cnt = 1;
  outp[(size_t)g * (NUM_EXPERTSC * HIDC) + k * HIDC + j] = acc / (float)cnt;
}

// ---------------- classifier, batched 4 experts ----------------
__global__ void kclsB(const float* __restrict__ hst, const float* __restrict__ w,
                      const float* __restrict__ b, float* __restrict__ outp) {
  int k = blockIdx.x >> 9;
  int g = blockIdx.x & 511;
  int c = threadIdx.x;
  if (c >= NUM_CLASSESC) return;
  float acc = 0.0f;
  for (int j = 0; j < HIDC; ++j)
    acc = __fadd_rn(acc, __fmul_rn(hst[(size_t)g * (NUM_EXPERTSC * HIDC) + k * HIDC + j],
                                   w[(size_t)k * HIDC * NUM_CLASSESC + j * NUM_CLASSESC + c]));
  outp[(size_t)g * (NUM_EXPERTSC * NUM_CLASSESC) + k * NUM_CLASSESC + c] =
      acc + b[k * NUM_CLASSESC + c];
}

// ---------------- launch ----------------
extern "C" void kernel_launch(void* const* d_in, const int* in_sizes, int n_in,
                              void* d_out, int out_size, void* d_ws, size_t ws_size,
                              hipStream_t stream) {
  const float* x    = (const float*)d_in[0];
  const int* eidx   = (const int*)d_in[1];
  const int* batch  = (const int*)d_in[2];
  const float* cw1  = (const float*)d_in[3];
  const float* cb1  = (const float*)d_in[4];
  const float* cw2  = (const float*)d_in[5];
  const float* cb2  = (const float*)d_in[6];
  const float* ceps = (const float*)d_in[7];
  const float* kw1  = (const float*)d_in[8];
  const float* kb1  = (const float*)d_in[9];
  const float* kw2  = (const float*)d_in[10];
  const float* kb2  = (const float*)d_in[11];
  const float* keps = (const float*)d_in[12];
  const float* nm_w1 = (const float*)d_in[13];
  const float* nm_b1 = (const float*)d_in[14];
  const float* nm_w2 = (const float*)d_in[15];
  const float* nm_b2 = (const float*)d_in[16];
  const float* em_w1 = (const float*)d_in[17];
  const float* em_b1 = (const float*)d_in[18];
  const float* em_w2 = (const float*)d_in[19];
  const float* em_b2 = (const float*)d_in[20];
  const float* fm_w1 = (const float*)d_in[21];
  const float* fm_b1 = (const float*)d_in[22];
  const float* fm_w2 = (const float*)d_in[23];
  const float* fm_b2 = (const float*)d_in[24];
  const float* cls_w = (const float*)d_in[25];
  const float* cls_b = (const float*)d_in[26];

  const int* src = eidx;
  const int* dstp = eidx + N_EDGESC;
  float* out = (float*)d_out;

  // output layout (floats)
  const size_t OFF_HST    = 20480;
  const size_t OFF_HORIG  = 282624;
  const size_t OFF_NODE   = 348160;
  const size_t OFF_EDGE   = 610304;
  const size_t OFF_FEAT   = 4804608;

  // workspace layout
  float* P  = (float*)d_ws;
  float* Zf = P;
  float* t2 = P + 2 * NH;
  float* t3 = P + 3 * NH;
  float* t4 = P + 4 * NH;
  unsigned short* hbB  = (unsigned short*)P;             // phase 2 alias
  unsigned short* aggB = (unsigned short*)(P + 2 * NH);  // phase 2 alias
  float* nl = P + 6 * NH;
  int* deg    = (int*)(nl + N_NODESC);
  int* offs   = deg + N_NODESC;
  int* curs   = offs + N_NODESC + 1;
  int* csr_s  = curs + N_NODESC;
  int* csr_e  = csr_s + N_EDGESC;
  int* bounds = csr_e + N_EDGESC;
  unsigned char* mcsr = (unsigned char*)(bounds + NUM_GRAPHSC + 3);  // 4*N_EDGES bytes
  unsigned short* Wt = (unsigned short*)(mcsr + 4 * (size_t)N_EDGESC + 64);  // 6*16384 bf16

  // host-side key derivation (JAX threefry, partitionable-mode split)
  uint32_t kk[NUM_EXPERTSC][3][2];
  for (int k = 0; k < NUM_EXPERTSC; ++k) {
    uint32_t f0, f1;
    threefry2x32(0u, 42u, 0u, (uint32_t)k, &f0, &f1);
    threefry2x32(f0, f1, 0u, 0u, &kk[k][0][0], &kk[k][0][1]);
    threefry2x32(f0, f1, 0u, 1u, &kk[k][1][0], &kk[k][1][1]);
    threefry2x32(f0, f1, 0u, 2u, &kk[k][2][0], &kk[k][2][1]);
  }

  // ---- CSR build (full graph) + weight prep ----
  hipMemsetAsync(deg, 0, N_NODESC * sizeof(int), stream);
  khist<<<N_EDGESC / 256, 256, 0, stream>>>(dstp, deg);
  kscan<<<1, 1024, 0, stream>>>(deg, offs);
  hipMemcpyAsync(curs, offs, N_NODESC * sizeof(int), hipMemcpyDeviceToDevice, stream);
  kfill<<<N_EDGESC / 256, 256, 0, stream>>>(src, dstp, curs, csr_s, csr_e);
  ksort<<<N_NODESC / 256, 256, 0, stream>>>(offs, csr_s, csr_e);
  kbounds<<<1, NUM_GRAPHSC, 0, stream>>>(batch, bounds);
  kprepW<<<48, 256, 0, stream>>>(kw1, kw2, Wt);

  const int GZ_GRID = N_NODESC * 64 / 256;   // 16384
  const int GEMM_GRID = N_NODESC / HIDC;     // 512

  // ---- clean encoder (f32, bit-exact) -> Zf ----
  for (int l = 0; l < NUM_LAYERSC; ++l) {
    const float* hin = (l == 0) ? x : t2;
    gather_z<<<GZ_GRID, 256, 0, stream>>>(hin, offs, csr_s, ceps, l, t3);
    gemm_f32<<<GEMM_GRID, 256, 0, stream>>>(t3, cw1 + (size_t)l * HIDC * HIDC,
                                            cb1 + l * HIDC, t4, 1);
    gemm_f32<<<GEMM_GRID, 256, 0, stream>>>(t4, cw2 + (size_t)l * HIDC * HIDC,
                                            cb2 + l * HIDC,
                                            (l == NUM_LAYERSC - 1) ? Zf : t2,
                                            (l < NUM_LAYERSC - 1) ? 1 : 0);
  }
  pool<<<NUM_GRAPHSC, HIDC, 0, stream>>>(Zf, bounds, out + OFF_HORIG, HIDC);

  // ---- phase 1: masks (f32 exact) ----
  for (int k = 0; k < NUM_EXPERTSC; ++k) {
    gemm_f32x4<<<4 * GEMM_GRID, 256, 0, stream>>>(
        Zf,
        nm_w1 + (size_t)k * HIDC * HIDC, fm_w1 + (size_t)k * HIDC * HIDC,
        em_w1 + (size_t)k * 2 * HIDC * HIDC,
        em_w1 + (size_t)k * 2 * HIDC * HIDC + HIDC * HIDC,
        nm_b1 + k * HIDC, fm_b1 + k * HIDC,
        nm_w2 + (size_t)k * HIDC, nm_b2 + k,
        kk[k][0][0], kk[k][0][1], out + OFF_NODE + k,
        t2, t3, t4);
    // feature mask: GEMM layer2 + fused decisions -> out
    gemm_feat<<<GEMM_GRID, 256, 0, stream>>>(t2, fm_w2 + (size_t)k * HIDC * HIDC,
                                             fm_b2 + (size_t)k * HIDC,
                                             kk[k][2][0], kk[k][2][1],
                                             out + OFF_FEAT + (size_t)k * HIDC);
    // edge mask (CSR order, fused decision, emits positional mcsr)
    edge_csrK<<<N_NODESC / 4, 256, 0, stream>>>(t3, t4, em_b1 + k * HIDC,
                                                em_w2 + (size_t)k * HIDC, em_b2 + k,
                                                offs, csr_s, csr_e,
                                                kk[k][1][0], kk[k][1][1],
                                                out + OFF_EDGE + k,
                                                mcsr + (size_t)k * N_EDGESC);
  }

  // ---- phase 2: masked encoders (fused-layer MFMA, batched, mask-skip) ----
  kmaskxB<<<4 * 8192, 256, 0, stream>>>(x, out + OFF_NODE, out + OFF_FEAT, hbB);
  for (int l = 0; l < NUM_LAYERSC; ++l) {
    gatherC<<<4 * GZ_GRID, 256, 0, stream>>>(hbB, offs, csr_s, mcsr, keps, l, aggB);
    gemm_mfma2<<<4 * GEMM_GRID, 256, 0, stream>>>(aggB,
                                                  Wt + (size_t)l * HIDC * HIDC,
                                                  Wt + (size_t)(3 + l) * HIDC * HIDC,
                                                  kb1 + l * HIDC, kb2 + l * HIDC,
                                                  hbB, (l < NUM_LAYERSC - 1) ? 1 : 0);
  }
  poolB<<<4 * NUM_GRAPHSC, HIDC, 0, stream>>>(hbB, bounds, out + OFF_HST);
  kclsB<<<4 * NUM_GRAPHSC, 64, 0, stream>>>(out + OFF_HST, cls_w, cls_b, out);
}

// Round 16
// 2471.811 us; speedup vs baseline: 1.0554x; 1.0554x over previous
//
#include <hip/hip_runtime.h>
#include <stdint.h>

#define N_NODESC 65536
#define N_EDGESC 1048576
#define HIDC 128
#define NUM_GRAPHSC 512
#define NUM_CLASSESC 10
#define NUM_EXPERTSC 4
#define NUM_LAYERSC 3

static const size_t NH = (size_t)N_NODESC * HIDC;

typedef __attribute__((ext_vector_type(8))) short short8v;   // 8 bf16 = 4 VGPR
typedef __attribute__((ext_vector_type(4))) float float4v;   // MFMA C/D

// ---------------- threefry2x32 (JAX-compatible, 20 rounds) ----------------
__host__ __device__ __forceinline__ uint32_t rotl32(uint32_t v, int r) {
  return (v << r) | (v >> (32 - r));
}
__host__ __device__ inline void threefry2x32(uint32_t k0, uint32_t k1,
                                             uint32_t x0, uint32_t x1,
                                             uint32_t* o0, uint32_t* o1) {
  uint32_t k2 = k0 ^ k1 ^ 0x1BD11BDAu;
  x0 += k0; x1 += k1;
#define TF_R(r) x0 += x1; x1 = rotl32(x1, r); x1 ^= x0;
  TF_R(13) TF_R(15) TF_R(26) TF_R(6)
  x0 += k1; x1 += k2 + 1u;
  TF_R(17) TF_R(29) TF_R(16) TF_R(24)
  x0 += k2; x1 += k0 + 2u;
  TF_R(13) TF_R(15) TF_R(26) TF_R(6)
  x0 += k0; x1 += k1 + 3u;
  TF_R(17) TF_R(29) TF_R(16) TF_R(24)
  x0 += k1; x1 += k2 + 4u;
  TF_R(13) TF_R(15) TF_R(26) TF_R(6)
  x0 += k2; x1 += k0 + 5u;
#undef TF_R
  *o0 = x0; *o1 = x1;
}

__device__ __forceinline__ float uniform_from_bits(uint32_t b) {
  float f = __uint_as_float((b >> 9) | 0x3f800000u) - 1.0f;
  const float mn = 1e-6f;
  const float mx = 1.0f - 1e-6f;
  return fmaxf(mn, __fadd_rn(__fmul_rn(f, __fsub_rn(mx, mn)), mn));
}

// f32-faithful hard-concrete decision (fast path + CR borderline replay)
__device__ __forceinline__ float hc_decide(float l, uint32_t key0, uint32_t key1,
                                           uint32_t i) {
  uint32_t o0, o1;
  threefry2x32(key0, key1, 0u, i, &o0, &o1);
  float u = uniform_from_bits(o0 ^ o1);
  float tf = -__logf(u);
  float gf = -__logf(tf);
  float margf = l + gf;
  if (fabsf(margf) > 1e-4f) return (margf > 0.0f) ? 1.0f : 0.0f;
  float t32 = (float)(-log((double)u));
  float g32 = (float)(-log((double)t32));
  float m32 = __fadd_rn(l, g32);
  float q = m32 / 0.1f;
  float e32 = (float)exp(-(double)q);
  float den = __fadd_rn(1.0f, e32);
  float s = 1.0f / den;
  return (s > 0.5f) ? 1.0f : 0.0f;
}

// ---------------- bf16 helpers ----------------
__device__ __forceinline__ float bf2f(unsigned short u) {
  return __uint_as_float(((uint32_t)u) << 16);
}
__device__ __forceinline__ unsigned short f2bf(float v) {
  uint32_t u = __float_as_uint(v);
  return (unsigned short)((u + 0x7FFFu + ((u >> 16) & 1u)) >> 16);
}

// ---------------- CSR build (full graph, eid-sorted for f32 exactness) -----
__global__ void khist(const int* __restrict__ dst, int* __restrict__ deg) {
  int e = blockIdx.x * 256 + threadIdx.x;
  if (e < N_EDGESC) atomicAdd(&deg[dst[e]], 1);
}

__global__ void kscan(const int* __restrict__ deg, int* __restrict__ offs) {
  __shared__ int part[1024];
  int t = threadIdx.x;
  int base = t * 64;
  int s = 0;
  for (int i = 0; i < 64; ++i) s += deg[base + i];
  part[t] = s;
  __syncthreads();
  for (int off = 1; off < 1024; off <<= 1) {
    int v = 0;
    if (t >= off) v = part[t - off];
    __syncthreads();
    part[t] += v;
    __syncthreads();
  }
  int run = part[t] - s;
  for (int i = 0; i < 64; ++i) {
    int d = deg[base + i];
    offs[base + i] = run;
    run += d;
  }
  if (t == 1023) offs[N_NODESC] = run;
}

__global__ void kfill(const int* __restrict__ src, const int* __restrict__ dst,
                      int* __restrict__ curs, int* __restrict__ csr_src,
                      int* __restrict__ csr_eid) {
  int e = blockIdx.x * 256 + threadIdx.x;
  if (e >= N_EDGESC) return;
  int d = dst[e];
  int p = atomicAdd(&curs[d], 1);
  csr_src[p] = src[e];
  csr_eid[p] = e;
}

__global__ void ksort(const int* __restrict__ offs, int* __restrict__ csr_src,
                      int* __restrict__ csr_eid) {
  int n = blockIdx.x * 256 + threadIdx.x;
  if (n >= N_NODESC) return;
  int s = offs[n], e = offs[n + 1];
  for (int i = s + 1; i < e; ++i) {
    int ke = csr_eid[i], ks = csr_src[i];
    int j = i - 1;
    while (j >= s && csr_eid[j] > ke) {
      csr_eid[j + 1] = csr_eid[j];
      csr_src[j + 1] = csr_src[j];
      --j;
    }
    csr_eid[j + 1] = ke;
    csr_src[j + 1] = ks;
  }
}

__global__ void kbounds(const int* __restrict__ batch, int* __restrict__ bounds) {
  int g = threadIdx.x;
  int lo = 0, hi = N_NODESC;
  while (lo < hi) {
    int mid = (lo + hi) >> 1;
    if (batch[mid] < g) lo = mid + 1; else hi = mid;
  }
  bounds[g] = lo;
  if (g == 0) bounds[NUM_GRAPHSC] = N_NODESC;
}

// ---------------- f32 GIN gather (clean encoder; bit-exact, 4-wide ILP) ----
__global__ void gather_z(const float* __restrict__ hin,
                         const int* __restrict__ offs,
                         const int* __restrict__ csr_src,
                         const float* __restrict__ epsArr, int l,
                         float* __restrict__ zout) {
  int gt = blockIdx.x * blockDim.x + threadIdx.x;
  int n = gt >> 6;
  int lane = gt & 63;
  if (n >= N_NODESC) return;
  int s = offs[n], e = offs[n + 1];
  float ax = 0.f, ay = 0.f;
  int i = s;
  for (; i + 4 <= e; i += 4) {
    int s0 = csr_src[i], s1 = csr_src[i + 1], s2 = csr_src[i + 2], s3 = csr_src[i + 3];
    const float2 v0 = *(const float2*)&hin[(size_t)s0 * HIDC + lane * 2];
    const float2 v1 = *(const float2*)&hin[(size_t)s1 * HIDC + lane * 2];
    const float2 v2 = *(const float2*)&hin[(size_t)s2 * HIDC + lane * 2];
    const float2 v3 = *(const float2*)&hin[(size_t)s3 * HIDC + lane * 2];
    ax = __fadd_rn(ax, v0.x); ay = __fadd_rn(ay, v0.y);
    ax = __fadd_rn(ax, v1.x); ay = __fadd_rn(ay, v1.y);
    ax = __fadd_rn(ax, v2.x); ay = __fadd_rn(ay, v2.y);
    ax = __fadd_rn(ax, v3.x); ay = __fadd_rn(ay, v3.y);
  }
  for (; i < e; ++i) {
    int sn = csr_src[i];
    const float2 v = *(const float2*)&hin[(size_t)sn * HIDC + lane * 2];
    ax = __fadd_rn(ax, v.x);
    ay = __fadd_rn(ay, v.y);
  }
  float ep = __fadd_rn(1.0f, epsArr[l]);
  const float2 hv = *(const float2*)&hin[(size_t)n * HIDC + lane * 2];
  ax = __fadd_rn(__fmul_rn(ep, hv.x), ax);
  ay = __fadd_rn(__fmul_rn(ep, hv.y), ay);
  float2 o; o.x = ax; o.y = ay;
  *(float2*)&zout[(size_t)n * HIDC + lane * 2] = o;
}

// ---------------- f32 K-split GEMM (bit-exact chain; 2 phases of K=64) -----
// LDS is HOISTED to the kernel (passed in) so multi-branch kernels share one
// 64KB allocation (round-15 bug: per-instantiation __shared__ doubled LDS).
// FMA chain k ascending, single accumulator. Swizzle byte = k*512 + MXOR(m)
// ^ KX(k) (staging writes 2-way, free per m136).
// NOTE: MXOR(m+4) != MXOR(m)+16 when (m&32) — compute MXOR at the exact row.
__device__ __forceinline__ int MXOR(int m) { return (m * 4) ^ ((m & 96) >> 1); }
__device__ __forceinline__ int KX(int k) { return ((k >> 2) & 7) << 4; }

template <typename EPI>
__device__ __forceinline__ void gemm_core(char* sXb, char* sWb,
                                          const float* __restrict__ Xf,
                                          const float* __restrict__ W,
                                          const float* __restrict__ bias,
                                          int doRelu, int tile, EPI epi) {
  const int tid = threadIdx.x;
  const size_t base = (size_t)tile * HIDC * HIDC;
  const int tm = (tid >> 4) << 3;
  const int tn = (tid & 15) << 3;
  const int xA = MXOR(tm), xA2 = MXOR(tm + 4);
  const int xB = MXOR(tn), xB2 = MXOR(tn + 4);

  float acc[8][8];
#pragma unroll
  for (int i = 0; i < 8; ++i)
#pragma unroll
    for (int j = 0; j < 8; ++j) acc[i][j] = 0.0f;

  for (int kh = 0; kh < 2; ++kh) {
    __syncthreads();
#pragma unroll
    for (int i = 0; i < 8; ++i) {
      int idx = tid + 256 * i;
      int m = idx >> 4;
      int kq = (idx & 15) * 4;
      float4 v = *(const float4*)(Xf + base + (size_t)m * HIDC + kh * 64 + kq);
      int mo = MXOR(m);
      *(float*)(sXb + (kq + 0) * 512 + (mo ^ KX(kq + 0))) = v.x;
      *(float*)(sXb + (kq + 1) * 512 + (mo ^ KX(kq + 1))) = v.y;
      *(float*)(sXb + (kq + 2) * 512 + (mo ^ KX(kq + 2))) = v.z;
      *(float*)(sXb + (kq + 3) * 512 + (mo ^ KX(kq + 3))) = v.w;
    }
#pragma unroll
    for (int i = 0; i < 8; ++i) {
      int idx = tid + 256 * i;
      int kk = idx >> 5;
      int n0 = (idx & 31) * 4;
      float4 v = *(const float4*)(W + (size_t)(kh * 64 + kk) * HIDC + n0);
      *(float4*)(sWb + kk * 512 + (MXOR(n0) ^ KX(kk))) = v;
    }
    __syncthreads();

#pragma unroll 4
    for (int kk = 0; kk < 64; ++kk) {
      int kx = KX(kk);
      float4 a0 = *(const float4*)(sXb + kk * 512 + (xA ^ kx));
      float4 a1 = *(const float4*)(sXb + kk * 512 + (xA2 ^ kx));
      float4 b0 = *(const float4*)(sWb + kk * 512 + (xB ^ kx));
      float4 b1 = *(const float4*)(sWb + kk * 512 + (xB2 ^ kx));
      float a[8] = {a0.x, a0.y, a0.z, a0.w, a1.x, a1.y, a1.z, a1.w};
      float b[8] = {b0.x, b0.y, b0.z, b0.w, b1.x, b1.y, b1.z, b1.w};
#pragma unroll
      for (int i = 0; i < 8; ++i)
#pragma unroll
        for (int j = 0; j < 8; ++j) acc[i][j] = fmaf(a[i], b[j], acc[i][j]);
    }
  }

  float bvals[8];
#pragma unroll
  for (int j = 0; j < 8; ++j) bvals[j] = bias ? bias[tn + j] : 0.0f;
#pragma unroll
  for (int i = 0; i < 8; ++i) {
    float r[8];
#pragma unroll
    for (int j = 0; j < 8; ++j) {
      float v = __fadd_rn(acc[i][j], bvals[j]);
      if (doRelu) v = fmaxf(v, 0.0f);
      r[j] = v;
    }
    epi(tile * HIDC + tm + i, tn, r);
  }
}

__global__ __launch_bounds__(256, 2)
void gemm_f32(const float* __restrict__ X, const float* __restrict__ W,
              const float* __restrict__ bias, float* __restrict__ O, int doRelu) {
  __shared__ char sXb[64 * 512];
  __shared__ char sWb[64 * 512];
  gemm_core(sXb, sWb, X, W, bias, doRelu, blockIdx.x,
            [&](int row, int tn, const float* r) {
              float* orow = O + (size_t)row * HIDC + tn;
              *(float4*)&orow[0] = *(const float4*)&r[0];
              *(float4*)&orow[4] = *(const float4*)&r[4];
            });
}

// 4 mask GEMMs of one expert; slice 0 fuses rowdot (16-lane butterfly) +
// node hard-concrete decision -> outNode (no global t1 round-trip).
__global__ __launch_bounds__(256, 2)
void gemm_f32x4(const float* __restrict__ X,
                const float* W0, const float* W1, const float* W2, const float* W3,
                const float* b0, const float* b1,
                const float* __restrict__ nw2, const float* __restrict__ nb2,
                uint32_t key0, uint32_t key1, float* __restrict__ outNode,
                float* o1, float* o2, float* o3) {
  __shared__ char sXb[64 * 512];
  __shared__ char sWb[64 * 512];
  int slice = blockIdx.x >> 9;
  int tile = blockIdx.x & 511;
  if (slice == 0) {
    const int tn0 = (threadIdx.x & 15) << 3;
    float w2v[8];
#pragma unroll
    for (int j = 0; j < 8; ++j) w2v[j] = nw2[tn0 + j];
    float b2s = nb2[0];
    gemm_core(sXb, sWb, X, W0, b0, 1, tile,
              [&](int row, int tn, const float* r) {
                float pd = 0.0f;
#pragma unroll
                for (int j = 0; j < 8; ++j) pd = fmaf(r[j], w2v[j], pd);
                pd += __shfl_xor(pd, 1, 16);
                pd += __shfl_xor(pd, 2, 16);
                pd += __shfl_xor(pd, 4, 16);
                pd += __shfl_xor(pd, 8, 16);
                if ((threadIdx.x & 15) == (row & 7)) {
                  float l = pd + b2s;
                  outNode[(size_t)row * NUM_EXPERTSC] =
                      hc_decide(l, key0, key1, (uint32_t)row);
                }
              });
  } else {
    const float* W; const float* bias; float* O; int relu;
    if (slice == 1)      { W = W1; bias = b1; O = o1; relu = 1; }
    else if (slice == 2) { W = W2; bias = nullptr; O = o2; relu = 0; }
    else                 { W = W3; bias = nullptr; O = o3; relu = 0; }
    gemm_core(sXb, sWb, X, W, bias, relu, tile,
              [&](int row, int tn, const float* r) {
                float* orow = O + (size_t)row * HIDC + tn;
                *(float4*)&orow[0] = *(const float4*)&r[0];
                *(float4*)&orow[4] = *(const float4*)&r[4];
              });
  }
}

// feat GEMM layer 2 + fused hard-concrete decisions -> out[OFF_FEAT..]
__global__ __launch_bounds__(256, 2)
void gemm_feat(const float* __restrict__ X, const float* __restrict__ W,
               const float* __restrict__ bias, uint32_t key0, uint32_t key1,
               float* __restrict__ outFeat /* + k*HIDC already */) {
  __shared__ char sXb[64 * 512];
  __shared__ char sWb[64 * 512];
  gemm_core(sXb, sWb, X, W, bias, 0, blockIdx.x,
            [&](int row, int tn, const float* r) {
              float d[8];
#pragma unroll
              for (int j = 0; j < 8; ++j)
                d[j] = hc_decide(r[j], key0, key1,
                                 (uint32_t)(row * HIDC + tn + j));
              float* orow = outFeat + (size_t)row * (NUM_EXPERTSC * HIDC) + tn;
              *(float4*)&orow[0] = *(const float4*)&d[0];
              *(float4*)&orow[4] = *(const float4*)&d[4];
            });
}

// ---------------- weight prep: f32 [k][n] -> bf16 transposed [n][k] --------
__global__ void kprepW(const float* __restrict__ kw1, const float* __restrict__ kw2,
                       unsigned short* __restrict__ Wt) {
  int t = blockIdx.x * 256 + threadIdx.x;   // 6 mats * 2048 uint4-chunks
  int mat = t >> 11;
  int r = t & 2047;
  int n = r >> 4;
  int kkc = r & 15;
  const float* W = (mat < 3) ? (kw1 + (size_t)mat * HIDC * HIDC)
                             : (kw2 + (size_t)(mat - 3) * HIDC * HIDC);
  unsigned short pk[8];
#pragma unroll
  for (int j = 0; j < 8; ++j)
    pk[j] = f2bf(W[(size_t)(kkc * 8 + j) * HIDC + n]);
  *(uint4*)(Wt + (size_t)mat * HIDC * HIDC + (size_t)n * HIDC + kkc * 8) =
      *(uint4*)pk;
}

// ------ bf16 MFMA fused layer: h2 = act2(relu(X@W1+b1)@W2+b2) --------------
// One 128x128 tile per block; h1 round-trips through LDS (bf16, same f2bf
// rounding as a global round-trip -> numerics identical).
// LDS swizzle: 16B-chunk index ^= (row&7).  Frag layouts per m89/m91.
__global__ __launch_bounds__(256, 2)
void gemm_mfma2(const unsigned short* __restrict__ Xpool,
                const unsigned short* __restrict__ Wt1,
                const unsigned short* __restrict__ Wt2,
                const float* __restrict__ bias1, const float* __restrict__ bias2,
                unsigned short* __restrict__ Opool, int doRelu2) {
  __shared__ unsigned short sX[128 * 128];
  __shared__ unsigned short sW[128 * 128];
  const int tid = threadIdx.x;
  const int kex = blockIdx.x >> 9;
  const int tile = blockIdx.x & 511;
  const unsigned short* X = Xpool + (size_t)kex * NH + (size_t)tile * HIDC * HIDC;
  unsigned short* O = Opool + (size_t)kex * NH + (size_t)tile * HIDC * HIDC;

  const int lane = tid & 63;
  const int wid = tid >> 6;
  const int wm = wid * 32;
  const int lrow = lane & 15;
  const int lk = (lane >> 4) * 4;
  union FU { uint2 u2[2]; short8v s8; };

#pragma unroll
  for (int i = 0; i < 8; ++i) {
    int idx = tid + 256 * i;
    int r = idx >> 4;
    int cc = idx & 15;
    uint4 vx = *(const uint4*)(X + (size_t)r * HIDC + cc * 8);
    uint4 vw = *(const uint4*)(Wt1 + (size_t)r * HIDC + cc * 8);
    int sc = (cc ^ (r & 7)) * 8;
    *(uint4*)(sX + r * HIDC + sc) = vx;
    *(uint4*)(sW + r * HIDC + sc) = vw;
  }
  __syncthreads();

  float4v acc[2][8];
#pragma unroll
  for (int rt = 0; rt < 2; ++rt)
#pragma unroll
    for (int nt = 0; nt < 8; ++nt) acc[rt][nt] = (float4v)0.0f;

  for (int kc = 0; kc < 128; kc += 32) {
    int kb = kc + lk;
    short8v afr[2], bfr[8];
#pragma unroll
    for (int rt = 0; rt < 2; ++rt) {
      int row = wm + rt * 16 + lrow;
      const unsigned short* basep = sX + row * HIDC;
      int s0 = (((kb) >> 3) ^ (row & 7)) * 8 + (kb & 7);
      int s1 = (((kb + 16) >> 3) ^ (row & 7)) * 8 + (kb & 7);
      FU u;
      u.u2[0] = *(const uint2*)(basep + s0);
      u.u2[1] = *(const uint2*)(basep + s1);
      afr[rt] = u.s8;
    }
#pragma unroll
    for (int nt = 0; nt < 8; ++nt) {
      int row = nt * 16 + lrow;
      const unsigned short* basep = sW + row * HIDC;
      int s0 = (((kb) >> 3) ^ (row & 7)) * 8 + (kb & 7);
      int s1 = (((kb + 16) >> 3) ^ (row & 7)) * 8 + (kb & 7);
      FU u;
      u.u2[0] = *(const uint2*)(basep + s0);
      u.u2[1] = *(const uint2*)(basep + s1);
      bfr[nt] = u.s8;
    }
#pragma unroll
    for (int rt = 0; rt < 2; ++rt)
#pragma unroll
      for (int nt = 0; nt < 8; ++nt)
        acc[rt][nt] = __builtin_amdgcn_mfma_f32_16x16x32_bf16(
            afr[rt], bfr[nt], acc[rt][nt], 0, 0, 0);
  }
  __syncthreads();

  // h1 -> sX (bf16, swizzled); stage W2 -> sW
#pragma unroll
  for (int nt = 0; nt < 8; ++nt) {
    float bv = bias1[nt * 16 + lrow];
#pragma unroll
    for (int rt = 0; rt < 2; ++rt) {
#pragma unroll
      for (int j = 0; j < 4; ++j) {
        float v = fmaxf(acc[rt][nt][j] + bv, 0.0f);
        int row = wm + rt * 16 + (lane >> 4) * 4 + j;
        int col = nt * 16 + lrow;
        int sc = (((col >> 3) ^ (row & 7)) * 8) + (col & 7);
        sX[row * HIDC + sc] = f2bf(v);
      }
    }
  }
#pragma unroll
  for (int i = 0; i < 8; ++i) {
    int idx = tid + 256 * i;
    int r = idx >> 4;
    int cc = idx & 15;
    uint4 vw = *(const uint4*)(Wt2 + (size_t)r * HIDC + cc * 8);
    *(uint4*)(sW + r * HIDC + ((cc ^ (r & 7)) * 8)) = vw;
  }
  __syncthreads();

#pragma unroll
  for (int rt = 0; rt < 2; ++rt)
#pragma unroll
    for (int nt = 0; nt < 8; ++nt) acc[rt][nt] = (float4v)0.0f;

  for (int kc = 0; kc < 128; kc += 32) {
    int kb = kc + lk;
    short8v afr[2], bfr[8];
#pragma unroll
    for (int rt = 0; rt < 2; ++rt) {
      int row = wm + rt * 16 + lrow;
      const unsigned short* basep = sX + row * HIDC;
      int s0 = (((kb) >> 3) ^ (row & 7)) * 8 + (kb & 7);
      int s1 = (((kb + 16) >> 3) ^ (row & 7)) * 8 + (kb & 7);
      FU u;
      u.u2[0] = *(const uint2*)(basep + s0);
      u.u2[1] = *(const uint2*)(basep + s1);
      afr[rt] = u.s8;
    }
#pragma unroll
    for (int nt = 0; nt < 8; ++nt) {
      int row = nt * 16 + lrow;
      const unsigned short* basep = sW + row * HIDC;
      int s0 = (((kb) >> 3) ^ (row & 7)) * 8 + (kb & 7);
      int s1 = (((kb + 16) >> 3) ^ (row & 7)) * 8 + (kb & 7);
      FU u;
      u.u2[0] = *(const uint2*)(basep + s0);
      u.u2[1] = *(const uint2*)(basep + s1);
      bfr[nt] = u.s8;
    }
#pragma unroll
    for (int rt = 0; rt < 2; ++rt)
#pragma unroll
      for (int nt = 0; nt < 8; ++nt)
        acc[rt][nt] = __builtin_amdgcn_mfma_f32_16x16x32_bf16(
            afr[rt], bfr[nt], acc[rt][nt], 0, 0, 0);
  }

#pragma unroll
  for (int nt = 0; nt < 8; ++nt) {
    float bv = bias2[nt * 16 + lrow];
#pragma unroll
    for (int rt = 0; rt < 2; ++rt) {
#pragma unroll
      for (int j = 0; j < 4; ++j) {
        float v = acc[rt][nt][j] + bv;
        if (doRelu2) v = fmaxf(v, 0.0f);
        int row = wm + rt * 16 + (lane >> 4) * 4 + j;
        O[(size_t)row * HIDC + nt * 16 + lrow] = f2bf(v);
      }
    }
  }
}

// -------- edge logits: 16-lane group per edge, 4 edges/wave concurrent ------
__global__ void edge_csrK(const float* __restrict__ A, const float* __restrict__ Bm,
                          const float* __restrict__ b1, const float* __restrict__ w2,
                          const float* __restrict__ b2,
                          const int* __restrict__ offs, const int* __restrict__ csr_src,
                          const int* __restrict__ csr_eid,
                          uint32_t key0, uint32_t key1,
                          float* __restrict__ outp, unsigned char* __restrict__ mcsr) {
  int n = blockIdx.x * 4 + (threadIdx.x >> 6);
  int lane = threadIdx.x & 63;
  int g = lane >> 4;
  int gl = lane & 15;
  const float4* Bv = (const float4*)&Bm[(size_t)n * HIDC + gl * 8];
  float4 b_lo = Bv[0], b_hi = Bv[1];
  float4 bb_lo = *(const float4*)&b1[gl * 8];
  float4 bb_hi = *(const float4*)&b1[gl * 8 + 4];
  float4 w_lo = *(const float4*)&w2[gl * 8];
  float4 w_hi = *(const float4*)&w2[gl * 8 + 4];
  float bscalar = b2[0];
  int s = offs[n], e = offs[n + 1];
  for (int i = s; i < e; i += 4) {
    int cnt = e - i; if (cnt > 4) cnt = 4;
    float p = 0.0f;
    if (g < cnt) {
      int sg = csr_src[i + g];
      const float4* Av = (const float4*)&A[(size_t)sg * HIDC + gl * 8];
      float4 a_lo = Av[0], a_hi = Av[1];
      float h;
      h = fmaxf(__fadd_rn(__fadd_rn(a_lo.x, b_lo.x), bb_lo.x), 0.0f); p = fmaf(h, w_lo.x, p);
      h = fmaxf(__fadd_rn(__fadd_rn(a_lo.y, b_lo.y), bb_lo.y), 0.0f); p = fmaf(h, w_lo.y, p);
      h = fmaxf(__fadd_rn(__fadd_rn(a_lo.z, b_lo.z), bb_lo.z), 0.0f); p = fmaf(h, w_lo.z, p);
      h = fmaxf(__fadd_rn(__fadd_rn(a_lo.w, b_lo.w), bb_lo.w), 0.0f); p = fmaf(h, w_lo.w, p);
      h = fmaxf(__fadd_rn(__fadd_rn(a_hi.x, b_hi.x), bb_hi.x), 0.0f); p = fmaf(h, w_hi.x, p);
      h = fmaxf(__fadd_rn(__fadd_rn(a_hi.y, b_hi.y), bb_hi.y), 0.0f); p = fmaf(h, w_hi.y, p);
      h = fmaxf(__fadd_rn(__fadd_rn(a_hi.z, b_hi.z), bb_hi.z), 0.0f); p = fmaf(h, w_hi.z, p);
      h = fmaxf(__fadd_rn(__fadd_rn(a_hi.w, b_hi.w), bb_hi.w), 0.0f); p = fmaf(h, w_hi.w, p);
    }
    p += __shfl_xor(p, 1, 16);
    p += __shfl_xor(p, 2, 16);
    p += __shfl_xor(p, 4, 16);
    p += __shfl_xor(p, 8, 16);
    if (g < cnt && gl == 0) {
      int eid = csr_eid[i + g];
      float l = p + bscalar;
      float mval = hc_decide(l, key0, key1, (uint32_t)eid);
      outp[(size_t)eid * NUM_EXPERTSC] = mval;
      mcsr[i + g] = (unsigned char)mval;
    }
  }
}

// ---------------- masked_x (bf16), batched 4 experts ----------------
__global__ void kmaskxB(const float* __restrict__ x, const float* __restrict__ nmaskb,
                        const float* __restrict__ fmaskb,
                        unsigned short* __restrict__ hbpool) {
  int k = blockIdx.x >> 13;
  int t = (blockIdx.x & 8191) * 256 + threadIdx.x;
  int n = t >> 5;
  int q = (t & 31) << 2;
  float nm = nmaskb[(size_t)n * NUM_EXPERTSC + k];
  float4 xv = *(const float4*)&x[(size_t)n * HIDC + q];
  float4 fv = *(const float4*)&fmaskb[(size_t)n * (NUM_EXPERTSC * HIDC) + k * HIDC + q];
  ushort2 p0, p1;
  p0.x = f2bf(xv.x * nm * fv.x); p0.y = f2bf(xv.y * nm * fv.y);
  p1.x = f2bf(xv.z * nm * fv.z); p1.y = f2bf(xv.w * nm * fv.w);
  uint2 pk; pk.x = (uint32_t)p0.x | ((uint32_t)p0.y << 16);
  pk.y = (uint32_t)p1.x | ((uint32_t)p1.y << 16);
  *(uint2*)(hbpool + (size_t)k * NH + (size_t)n * HIDC + q) = pk;
}

// -------- bf16 GIN gather, full CSR + positional mask bytes ----------------
__global__ void gatherC(const unsigned short* __restrict__ hpool,
                        const int* __restrict__ offs,
                        const int* __restrict__ csr_src,
                        const unsigned char* __restrict__ mcsr,
                        const float* __restrict__ epsArr, int l,
                        unsigned short* __restrict__ aggpool) {
  int gid = blockIdx.x * 4 + (threadIdx.x >> 6);
  int lane = threadIdx.x & 63;
  int k = gid >> 16;
  int n = gid & 65535;
  const unsigned short* h = hpool + (size_t)k * NH;
  const unsigned char* mc = mcsr + (size_t)k * N_EDGESC;
  int s = offs[n], e = offs[n + 1];
  float ax = 0.f, ay = 0.f;
  for (int base = s; base < e; base += 64) {
    int j = base + lane;
    int valid = (j < e);
    int keep = valid ? (mc[j] != 0) : 0;
    int srcj = valid ? csr_src[j] : 0;
    unsigned long long ball = __ballot(keep);
    while (ball) {
      int l0 = -1, l1 = -1, l2 = -1, l3 = -1;
      l0 = __ffsll((unsigned long long)ball) - 1; ball &= ball - 1;
      if (ball) { l1 = __ffsll((unsigned long long)ball) - 1; ball &= ball - 1; }
      if (ball) { l2 = __ffsll((unsigned long long)ball) - 1; ball &= ball - 1; }
      if (ball) { l3 = __ffsll((unsigned long long)ball) - 1; ball &= ball - 1; }
      int s0 = __shfl(srcj, l0, 64);
      int s1 = (l1 >= 0) ? __shfl(srcj, l1, 64) : 0;
      int s2 = (l2 >= 0) ? __shfl(srcj, l2, 64) : 0;
      int s3 = (l3 >= 0) ? __shfl(srcj, l3, 64) : 0;
      uint32_t v0 = *(const uint32_t*)(h + (size_t)s0 * HIDC + lane * 2);
      uint32_t v1 = (l1 >= 0) ? *(const uint32_t*)(h + (size_t)s1 * HIDC + lane * 2) : 0;
      uint32_t v2 = (l2 >= 0) ? *(const uint32_t*)(h + (size_t)s2 * HIDC + lane * 2) : 0;
      uint32_t v3 = (l3 >= 0) ? *(const uint32_t*)(h + (size_t)s3 * HIDC + lane * 2) : 0;
      ax += __uint_as_float(v0 << 16); ay += __uint_as_float(v0 & 0xFFFF0000u);
      if (l1 >= 0) { ax += __uint_as_float(v1 << 16); ay += __uint_as_float(v1 & 0xFFFF0000u); }
      if (l2 >= 0) { ax += __uint_as_float(v2 << 16); ay += __uint_as_float(v2 & 0xFFFF0000u); }
      if (l3 >= 0) { ax += __uint_as_float(v3 << 16); ay += __uint_as_float(v3 & 0xFFFF0000u); }
    }
  }
  float ep = 1.0f + epsArr[l];
  uint32_t hv = *(const uint32_t*)(h + (size_t)n * HIDC + lane * 2);
  ax = fmaf(ep, __uint_as_float(hv << 16), ax);
  ay = fmaf(ep, __uint_as_float(hv & 0xFFFF0000u), ay);
  uint32_t pk = (uint32_t)f2bf(ax) | ((uint32_t)f2bf(ay) << 16);
  *(uint32_t*)(aggpool + (size_t)k * NH + (size_t)n * HIDC + lane * 2) = pk;
}

// ---------------- mean pool (f32, clean Z) ----------------
__global__ void pool(const float* __restrict__ h, const int* __restrict__ bounds,
                     float* __restrict__ outp, int rowStride) {
  int g = blockIdx.x, j = threadIdx.x;
  int s = bounds[g], e = bounds[g + 1];
  float acc = 0.0f;
  for (int i = s; i < e; ++i) acc = __fadd_rn(acc, h[(size_t)i * HIDC + j]);
  int cnt = e - s; if (cnt < 1) cnt = 1;
  outp[(size_t)g * rowStride + j] = acc / (float)cnt;
}

// ---------------- mean pool (bf16 input), batched 4 experts ----------------
__global__ void poolB(const unsigned short* __restrict__ hbpool,
                      const int* __restrict__ bounds, float* __restrict__ outp) {
  int k = blockIdx.x >> 9;
  int g = blockIdx.x & 511;
  int j = threadIdx.x;
  const unsigned short* h = hbpool + (size_t)k * NH;
  int s = bounds[g], e = bounds[g + 1];
  float acc = 0.0f;
  for (int i = s; i < e; ++i) acc += bf2f(h[(size_t)i * HIDC + j]);
  int cnt = e - s; if (cnt < 1) cnt = 1;
  outp[(size_t)g * (NUM_EXPERTSC * HIDC) + k * HIDC + j] = acc / (float)cnt;
}

// ---------------- classifier, batched 4 experts ----------------
__global__ void kclsB(const float* __restrict__ hst, const float* __restrict__ w,
                      const float* __restrict__ b, float* __restrict__ outp) {
  int k = blockIdx.x >> 9;
  int g = blockIdx.x & 511;
  int c = threadIdx.x;
  if (c >= NUM_CLASSESC) return;
  float acc = 0.0f;
  for (int j = 0; j < HIDC; ++j)
    acc = __fadd_rn(acc, __fmul_rn(hst[(size_t)g * (NUM_EXPERTSC * HIDC) + k * HIDC + j],
                                   w[(size_t)k * HIDC * NUM_CLASSESC + j * NUM_CLASSESC + c]));
  outp[(size_t)g * (NUM_EXPERTSC * NUM_CLASSESC) + k * NUM_CLASSESC + c] =
      acc + b[k * NUM_CLASSESC + c];
}

// ---------------- launch ----------------
extern "C" void kernel_launch(void* const* d_in, const int* in_sizes, int n_in,
                              void* d_out, int out_size, void* d_ws, size_t ws_size,
                              hipStream_t stream) {
  const float* x    = (const float*)d_in[0];
  const int* eidx   = (const int*)d_in[1];
  const int* batch  = (const int*)d_in[2];
  const float* cw1  = (const float*)d_in[3];
  const float* cb1  = (const float*)d_in[4];
  const float* cw2  = (const float*)d_in[5];
  const float* cb2  = (const float*)d_in[6];
  const float* ceps = (const float*)d_in[7];
  const float* kw1  = (const float*)d_in[8];
  const float* kb1  = (const float*)d_in[9];
  const float* kw2  = (const float*)d_in[10];
  const float* kb2  = (const float*)d_in[11];
  const float* keps = (const float*)d_in[12];
  const float* nm_w1 = (const float*)d_in[13];
  const float* nm_b1 = (const float*)d_in[14];
  const float* nm_w2 = (const float*)d_in[15];
  const float* nm_b2 = (const float*)d_in[16];
  const float* em_w1 = (const float*)d_in[17];
  const float* em_b1 = (const float*)d_in[18];
  const float* em_w2 = (const float*)d_in[19];
  const float* em_b2 = (const float*)d_in[20];
  const float* fm_w1 = (const float*)d_in[21];
  const float* fm_b1 = (const float*)d_in[22];
  const float* fm_w2 = (const float*)d_in[23];
  const float* fm_b2 = (const float*)d_in[24];
  const float* cls_w = (const float*)d_in[25];
  const float* cls_b = (const float*)d_in[26];

  const int* src = eidx;
  const int* dstp = eidx + N_EDGESC;
  float* out = (float*)d_out;

  // output layout (floats)
  const size_t OFF_HST    = 20480;
  const size_t OFF_HORIG  = 282624;
  const size_t OFF_NODE   = 348160;
  const size_t OFF_EDGE   = 610304;
  const size_t OFF_FEAT   = 4804608;

  // workspace layout
  float* P  = (float*)d_ws;
  float* Zf = P;
  float* t2 = P + 2 * NH;
  float* t3 = P + 3 * NH;
  float* t4 = P + 4 * NH;
  unsigned short* hbB  = (unsigned short*)P;             // phase 2 alias
  unsigned short* aggB = (unsigned short*)(P + 2 * NH);  // phase 2 alias
  float* nl = P + 6 * NH;
  int* deg    = (int*)(nl + N_NODESC);
  int* offs   = deg + N_NODESC;
  int* curs   = offs + N_NODESC + 1;
  int* csr_s  = curs + N_NODESC;
  int* csr_e  = csr_s + N_EDGESC;
  int* bounds = csr_e + N_EDGESC;
  unsigned char* mcsr = (unsigned char*)(bounds + NUM_GRAPHSC + 3);  // 4*N_EDGES bytes
  unsigned short* Wt = (unsigned short*)(mcsr + 4 * (size_t)N_EDGESC + 64);  // 6*16384 bf16

  // host-side key derivation (JAX threefry, partitionable-mode split)
  uint32_t kk[NUM_EXPERTSC][3][2];
  for (int k = 0; k < NUM_EXPERTSC; ++k) {
    uint32_t f0, f1;
    threefry2x32(0u, 42u, 0u, (uint32_t)k, &f0, &f1);
    threefry2x32(f0, f1, 0u, 0u, &kk[k][0][0], &kk[k][0][1]);
    threefry2x32(f0, f1, 0u, 1u, &kk[k][1][0], &kk[k][1][1]);
    threefry2x32(f0, f1, 0u, 2u, &kk[k][2][0], &kk[k][2][1]);
  }

  // ---- CSR build (full graph) + weight prep ----
  hipMemsetAsync(deg, 0, N_NODESC * sizeof(int), stream);
  khist<<<N_EDGESC / 256, 256, 0, stream>>>(dstp, deg);
  kscan<<<1, 1024, 0, stream>>>(deg, offs);
  hipMemcpyAsync(curs, offs, N_NODESC * sizeof(int), hipMemcpyDeviceToDevice, stream);
  kfill<<<N_EDGESC / 256, 256, 0, stream>>>(src, dstp, curs, csr_s, csr_e);
  ksort<<<N_NODESC / 256, 256, 0, stream>>>(offs, csr_s, csr_e);
  kbounds<<<1, NUM_GRAPHSC, 0, stream>>>(batch, bounds);
  kprepW<<<48, 256, 0, stream>>>(kw1, kw2, Wt);

  const int GZ_GRID = N_NODESC * 64 / 256;   // 16384
  const int GEMM_GRID = N_NODESC / HIDC;     // 512

  // ---- clean encoder (f32, bit-exact) -> Zf ----
  for (int l = 0; l < NUM_LAYERSC; ++l) {
    const float* hin = (l == 0) ? x : t2;
    gather_z<<<GZ_GRID, 256, 0, stream>>>(hin, offs, csr_s, ceps, l, t3);
    gemm_f32<<<GEMM_GRID, 256, 0, stream>>>(t3, cw1 + (size_t)l * HIDC * HIDC,
                                            cb1 + l * HIDC, t4, 1);
    gemm_f32<<<GEMM_GRID, 256, 0, stream>>>(t4, cw2 + (size_t)l * HIDC * HIDC,
                                            cb2 + l * HIDC,
                                            (l == NUM_LAYERSC - 1) ? Zf : t2,
                                            (l < NUM_LAYERSC - 1) ? 1 : 0);
  }
  pool<<<NUM_GRAPHSC, HIDC, 0, stream>>>(Zf, bounds, out + OFF_HORIG, HIDC);

  // ---- phase 1: masks (f32 exact) ----
  for (int k = 0; k < NUM_EXPERTSC; ++k) {
    gemm_f32x4<<<4 * GEMM_GRID, 256, 0, stream>>>(
        Zf,
        nm_w1 + (size_t)k * HIDC * HIDC, fm_w1 + (size_t)k * HIDC * HIDC,
        em_w1 + (size_t)k * 2 * HIDC * HIDC,
        em_w1 + (size_t)k * 2 * HIDC * HIDC + HIDC * HIDC,
        nm_b1 + k * HIDC, fm_b1 + k * HIDC,
        nm_w2 + (size_t)k * HIDC, nm_b2 + k,
        kk[k][0][0], kk[k][0][1], out + OFF_NODE + k,
        t2, t3, t4);
    // feature mask: GEMM layer2 + fused decisions -> out
    gemm_feat<<<GEMM_GRID, 256, 0, stream>>>(t2, fm_w2 + (size_t)k * HIDC * HIDC,
                                             fm_b2 + (size_t)k * HIDC,
                                             kk[k][2][0], kk[k][2][1],
                                             out + OFF_FEAT + (size_t)k * HIDC);
    // edge mask (CSR order, fused decision, emits positional mcsr)
    edge_csrK<<<N_NODESC / 4, 256, 0, stream>>>(t3, t4, em_b1 + k * HIDC,
                                                em_w2 + (size_t)k * HIDC, em_b2 + k,
                                                offs, csr_s, csr_e,
                                                kk[k][1][0], kk[k][1][1],
                                                out + OFF_EDGE + k,
                                                mcsr + (size_t)k * N_EDGESC);
  }

  // ---- phase 2: masked encoders (fused-layer MFMA, batched, mask-skip) ----
  kmaskxB<<<4 * 8192, 256, 0, stream>>>(x, out + OFF_NODE, out + OFF_FEAT, hbB);
  for (int l = 0; l < NUM_LAYERSC; ++l) {
    gatherC<<<4 * GZ_GRID, 256, 0, stream>>>(hbB, offs, csr_s, mcsr, keps, l, aggB);
    gemm_mfma2<<<4 * GEMM_GRID, 256, 0, stream>>>(aggB,
                                                  Wt + (size_t)l * HIDC * HIDC,
                                                  Wt + (size_t)(3 + l) * HIDC * HIDC,
                                                  kb1 + l * HIDC, kb2 + l * HIDC,
                                                  hbB, (l < NUM_LAYERSC - 1) ? 1 : 0);
  }
  poolB<<<4 * NUM_GRAPHSC, HIDC, 0, stream>>>(hbB, bounds, out + OFF_HST);
  kclsB<<<4 * NUM_GRAPHSC, 64, 0, stream>>>(out + OFF_HST, cls_w, cls_b, out);
}